// Round 7
// baseline (462.897 us; speedup 1.0000x reference)
//
#include <hip/hip_runtime.h>
#include <math.h>

#define T_SEQ 2048
#define C_DIM 2048
#define NH    16
#define NG    4
#define DH    128
#define BATCH 2

typedef unsigned short u16;
typedef __bf16 bf16_t;
typedef bf16_t bf16x8 __attribute__((ext_vector_type(8)));
typedef float  f32x4  __attribute__((ext_vector_type(4)));

static __device__ __forceinline__ u16 f2bf(float f) {
    return __builtin_bit_cast(u16, (__bf16)f);
}

// async global->LDS, 16B per lane. lds must be wave-uniform base; HW adds lane*16.
static __device__ __forceinline__ void gll16(const void* g, void* lds) {
    __builtin_amdgcn_global_load_lds(
        (const __attribute__((address_space(1))) void*)(unsigned long long)(g),
        (__attribute__((address_space(3))) void*)(unsigned int)(unsigned long long)(lds),
        16, 0, 0);
}

// ---------------------------------------------------------------------------
// fused fp32->bf16 cast for x, Wq, Wk, Wv (8 elems/thread, flat if-chain)
// chunk counts: x 1048576 | Wq 524288 | Wk 131072 | Wv 131072  (sum = 7168*256)
// ---------------------------------------------------------------------------
__global__ __launch_bounds__(256)
void cast_multi(const float* __restrict__ x,  const float* __restrict__ wq,
                const float* __restrict__ wk, const float* __restrict__ wv,
                u16* __restrict__ xo, u16* __restrict__ wqo,
                u16* __restrict__ wko, u16* __restrict__ wvo) {
    int i = blockIdx.x * 256 + threadIdx.x;
    const float* src; u16* dst; int off;
    if (i < 1048576)      { src = x;  dst = xo;  off = i; }
    else if (i < 1572864) { src = wq; dst = wqo; off = i - 1048576; }
    else if (i < 1703936) { src = wk; dst = wko; off = i - 1572864; }
    else                  { src = wv; dst = wvo; off = i - 1703936; }
    const float4* p = (const float4*)src + (size_t)off * 2;
    float4 a = p[0], b = p[1];
    u16 u[8] = {f2bf(a.x), f2bf(a.y), f2bf(a.z), f2bf(a.w),
                f2bf(b.x), f2bf(b.y), f2bf(b.z), f2bf(b.w)};
    *(uint4*)(dst + (size_t)off * 8) = *(const uint4*)u;
}

__global__ __launch_bounds__(256)
void cast_f32_bf16(const float* __restrict__ in, u16* __restrict__ out, int n8) {
    int i = blockIdx.x * 256 + threadIdx.x;
    if (i >= n8) return;
    const float4* p = (const float4*)in + (size_t)i * 2;
    float4 a = p[0], b = p[1];
    u16 u[8] = {f2bf(a.x), f2bf(a.y), f2bf(a.z), f2bf(a.w),
                f2bf(b.x), f2bf(b.y), f2bf(b.z), f2bf(b.w)};
    *(uint4*)(out + (size_t)i * 8) = *(const uint4*)u;
}

// ---------------------------------------------------------------------------
// C(fp32, M x N) = A_bf16(M,K) @ B_bf16(N,K)^T (+bias)
// 128x128 tile, BK=32, 4 waves, each wave 64x64 (4x4 MFMA 16x16x32).
// ---------------------------------------------------------------------------
static __device__ __forceinline__ void gemm_body(
        u16* As, u16* Bs,
        const u16* __restrict__ A, const u16* __restrict__ B,
        const float* __restrict__ bias, float* __restrict__ C,
        int N, int K, int m0, int n0) {
    const int t    = threadIdx.x;
    const int lane = t & 63, w = t >> 6;
    const int l15  = lane & 15, quad = lane >> 4;
    const int wr   = w >> 1, wc = w & 1;

    f32x4 acc[4][4];
#pragma unroll
    for (int mt = 0; mt < 4; ++mt)
#pragma unroll
        for (int nt = 0; nt < 4; ++nt) acc[mt][nt] = (f32x4){0.f, 0.f, 0.f, 0.f};

    const int off0 = w*2048 + lane*16;
    const int r0 = off0 >> 6,          c0 = (off0 & 63) >> 1;
    const int r1 = (off0+1024) >> 6,   c1 = ((off0+1024) & 63) >> 1;
    const u16* Ag0 = A + (size_t)(m0 + r0) * K + c0;
    const u16* Ag1 = A + (size_t)(m0 + r1) * K + c1;
    const u16* Bg0 = B + (size_t)(n0 + r0) * K + c0;
    const u16* Bg1 = B + (size_t)(n0 + r1) * K + c1;
    char* AsB = (char*)As; char* BsB = (char*)Bs;
    const int ldsOff0 = w*2048, ldsOff1 = w*2048 + 1024;

    for (int k0 = 0; k0 < K; k0 += 32) {
        gll16(Ag0 + k0, AsB + ldsOff0);
        gll16(Ag1 + k0, AsB + ldsOff1);
        gll16(Bg0 + k0, BsB + ldsOff0);
        gll16(Bg1 + k0, BsB + ldsOff1);
        __syncthreads();
        bf16x8 af[4], bf[4];
#pragma unroll
        for (int mt = 0; mt < 4; ++mt)
            af[mt] = __builtin_bit_cast(bf16x8,
                *(const uint4*)&As[(wr*64 + mt*16 + l15)*32 + quad*8]);
#pragma unroll
        for (int nt = 0; nt < 4; ++nt)
            bf[nt] = __builtin_bit_cast(bf16x8,
                *(const uint4*)&Bs[(wc*64 + nt*16 + l15)*32 + quad*8]);
#pragma unroll
        for (int mt = 0; mt < 4; ++mt)
#pragma unroll
            for (int nt = 0; nt < 4; ++nt)
                acc[mt][nt] = __builtin_amdgcn_mfma_f32_16x16x32_bf16(
                                  af[mt], bf[nt], acc[mt][nt], 0, 0, 0);
        __syncthreads();
    }

#pragma unroll
    for (int mt = 0; mt < 4; ++mt)
#pragma unroll
        for (int nt = 0; nt < 4; ++nt) {
            const int col = n0 + wc*64 + nt*16 + l15;
            const float bv = bias ? bias[col] : 0.f;
#pragma unroll
            for (int r = 0; r < 4; ++r) {
                const int row = m0 + wr*64 + mt*16 + quad*4 + r;
                C[(size_t)row * N + col] = acc[mt][nt][r] + bv;
            }
        }
}

__global__ __launch_bounds__(256)
void gemm_nt_bf16(const u16* __restrict__ A, const u16* __restrict__ B,
                  const float* __restrict__ bias, float* __restrict__ C,
                  int N, int K) {
    __shared__ __align__(16) u16 As[128*32];
    __shared__ __align__(16) u16 Bs[128*32];
    gemm_body(As, Bs, A, B, bias, C, N, K, blockIdx.y*128, blockIdx.x*128);
}

// fused Q/K/V projections: blockIdx.x 0..15 -> Q cols, 16..19 -> K, 20..23 -> V
__global__ __launch_bounds__(256)
void gemm_qkv(const u16* __restrict__ A,  const u16* __restrict__ Bq,
              const u16* __restrict__ Bk, const u16* __restrict__ Bv,
              float* __restrict__ Cq, float* __restrict__ Ck, float* __restrict__ Cv) {
    __shared__ __align__(16) u16 As[128*32];
    __shared__ __align__(16) u16 Bs[128*32];
    const int bx = blockIdx.x;
    const u16* B; float* C; int N, n0;
    if (bx < 16)      { B = Bq; C = Cq; N = 2048; n0 = bx * 128; }
    else if (bx < 20) { B = Bk; C = Ck; N = 512;  n0 = (bx-16) * 128; }
    else              { B = Bv; C = Cv; N = 512;  n0 = (bx-20) * 128; }
    gemm_body(As, Bs, A, B, nullptr, C, N, 2048, blockIdx.y*128, n0);
}

// ---------------------------------------------------------------------------
// Fused RMSNorm + RoPE for q and k, fp32 in -> bf16 out.
// blocks [0, 16384): q rows; [16384, 20480): k rows. One wave per D=128 row.
// ---------------------------------------------------------------------------
__global__ __launch_bounds__(256)
void rmsnorm_rope_qk(const float* __restrict__ qf, const float* __restrict__ kf,
                     const float* __restrict__ qw, const float* __restrict__ kw,
                     u16* __restrict__ qo, u16* __restrict__ ko) {
    const int blk  = blockIdx.x;
    const int sub  = threadIdx.x >> 6;
    const int lane = threadIdx.x & 63;
    const float* in; const float* w; u16* out; int row, nheads; float scale;
    if (blk < 16384) {
        in = qf; w = qw; out = qo; nheads = NH; scale = 0.08838834764831845f;
        row = blk * 4 + sub;
    } else {
        in = kf; w = kw; out = ko; nheads = NG; scale = 1.0f;
        row = (blk - 16384) * 4 + sub;
    }
    const float* p = in + (size_t)row * 128;
    float x1 = p[lane], x2 = p[lane + 64];
    float ss = x1*x1 + x2*x2;
#pragma unroll
    for (int off = 32; off >= 1; off >>= 1) ss += __shfl_xor(ss, off, 64);
    float inv = 1.0f / (sqrtf(ss * (1.0f/128.0f)) + 1e-6f);
    float x1n = w[lane]      * x1 * inv;
    float x2n = w[lane + 64] * x2 * inv;
    int tpos = (row / nheads) & (T_SEQ - 1);
    float invfreq = powf(10000.0f, -(float)lane / 64.0f);
    float s, c;
    sincosf((float)tpos * invfreq, &s, &c);
    out[(size_t)row*128 + lane]      = f2bf((x1n * c + x2n * s) * scale);
    out[(size_t)row*128 + lane + 64] = f2bf((x2n * c - x1n * s) * scale);
}

// ---------------------------------------------------------------------------
// V cast fp32->bf16 + transpose: v (B,T,G,D) -> vt (B,G,D,T).
// ---------------------------------------------------------------------------
__global__ __launch_bounds__(256)
void v_cast_transpose(const float* __restrict__ v, u16* __restrict__ vt) {
    __shared__ u16 Lt[128 * 66];
    const int t  = threadIdx.x;
    const int t0 = blockIdx.x * 64;
    const int bg = blockIdx.y;
    const int b  = bg / NG, g = bg % NG;
#pragma unroll
    for (int rep = 0; rep < 8; ++rep) {
        int idx = rep * 256 + t;
        int i   = idx >> 5;
        int c   = idx & 31;
        float4 f = *(const float4*)(v + ((size_t)(b*T_SEQ + t0 + i)*NG + g)*DH + c*4);
        Lt[(c*4+0)*66 + i] = f2bf(f.x);
        Lt[(c*4+1)*66 + i] = f2bf(f.y);
        Lt[(c*4+2)*66 + i] = f2bf(f.z);
        Lt[(c*4+3)*66 + i] = f2bf(f.w);
    }
    __syncthreads();
#pragma unroll
    for (int rep = 0; rep < 4; ++rep) {
        int idx = rep * 256 + t;
        int d = idx >> 3, c = idx & 7;
        const u16* src = &Lt[d*66 + c*8];
        uint4 val;
        val.x = *(const unsigned int*)(src + 0);
        val.y = *(const unsigned int*)(src + 2);
        val.z = *(const unsigned int*)(src + 4);
        val.w = *(const unsigned int*)(src + 6);
        *(uint4*)(vt + ((size_t)(bg*DH + d))*T_SEQ + t0 + c*8) = val;
    }
}

// ---------------------------------------------------------------------------
// MFMA flash attention v5: 4 waves, wave = 32 q-rows x 1 head (2 A-frags),
// so every K/V fragment read from LDS feeds 2 MFMAs (halves LDS BW/work).
// K/V staged once per block, shared by the 4 heads of the GQA group.
// chunk pairing balances CU load; K/V tile t+1 prefetched into VGPRs.
// ---------------------------------------------------------------------------
#define KPAD 136
#define VPAD 72
#define PPAD 72

__global__ __launch_bounds__(256, 2)
void flash_attn_mfma(const u16* __restrict__ qh, const u16* __restrict__ kh,
                     const u16* __restrict__ vt, u16* __restrict__ y) {
    __shared__ __align__(16) u16 Ks [64  * KPAD];   // 64 keys x 128 d
    __shared__ __align__(16) u16 Vts[128 * VPAD];   // 128 d  x 64 keys
    __shared__ __align__(16) u16 Ps [128 * PPAD];   // 4 waves x 32 rows x 64 keys

    const int t    = threadIdx.x;
    const int lane = t & 63, w = t >> 6;            // w = 0..3
    const int l15  = lane & 15, quad = lane >> 4;
    const int bg   = blockIdx.y;
    const int b    = bg >> 2, g = bg & 3;
    const int chunk = b ? (int)blockIdx.x : (63 - (int)blockIdx.x);
    const int q0   = chunk * 32;
    const int h    = g * (NH / NG) + w;

    const float L2E = 1.4426950408889634f;

    // Q fragments: 2 m-tiles x 4 k-chunks
    bf16x8 aq[2][4];
#pragma unroll
    for (int m = 0; m < 2; ++m) {
        const u16* qp = qh + ((size_t)(b*T_SEQ + q0 + m*16 + l15) * NH + h) * DH;
#pragma unroll
        for (int kc = 0; kc < 4; ++kc)
            aq[m][kc] = __builtin_bit_cast(bf16x8, *(const uint4*)(qp + kc*32 + quad*8));
    }

    f32x4 accO[2][8];
#pragma unroll
    for (int m = 0; m < 2; ++m)
#pragma unroll
        for (int nd = 0; nd < 8; ++nd) accO[m][nd] = (f32x4){0.f, 0.f, 0.f, 0.f};
    float ls[2][4] = {{0.f,0.f,0.f,0.f},{0.f,0.f,0.f,0.f}};

    // staging geometry (256 threads): K 64x16 chunks, V 128x8 chunks; 4 each
    const int kr = t >> 4, kc16 = t & 15;
    const int vd = t >> 3, vc8  = t & 7;
    const u16* kgb = kh + ((size_t)b*T_SEQ*NG + g)*DH;
    const u16* vgb = vt + ((size_t)(b*NG + g)*DH)*T_SEQ;

    uint4 kreg[4], vreg[4];
#pragma unroll
    for (int rep = 0; rep < 4; ++rep) {
        kreg[rep] = *(const uint4*)(kgb + (size_t)(kr + rep*16) * NG*DH + kc16*8);
        vreg[rep] = *(const uint4*)(vgb + (size_t)(vd + rep*32) * T_SEQ + vc8*8);
    }

    const int ktiles = q0 / 64 + 1;
    for (int kt = 0; kt < ktiles; ++kt) {
        // --- regs -> LDS ---
#pragma unroll
        for (int rep = 0; rep < 4; ++rep) {
            *(uint4*)&Ks [(kr + rep*16)*KPAD + kc16*8] = kreg[rep];
            *(uint4*)&Vts[(vd + rep*32)*VPAD + vc8*8]  = vreg[rep];
        }
        __syncthreads();

        // --- prefetch tile kt+1 (overlaps compute) ---
        if (kt + 1 < ktiles) {
            const int k1 = (kt + 1) * 64;
#pragma unroll
            for (int rep = 0; rep < 4; ++rep) {
                kreg[rep] = *(const uint4*)(kgb + (size_t)(k1 + kr + rep*16) * NG*DH + kc16*8);
                vreg[rep] = *(const uint4*)(vgb + (size_t)(vd + rep*32) * T_SEQ + k1 + vc8*8);
            }
        }

        const int k0 = kt * 64;
        // --- S = Q K^T: each bk feeds 2 MFMAs ---
        f32x4 accS[2][4];
#pragma unroll
        for (int m = 0; m < 2; ++m)
#pragma unroll
            for (int nt = 0; nt < 4; ++nt) accS[m][nt] = (f32x4){0.f, 0.f, 0.f, 0.f};
#pragma unroll
        for (int nt = 0; nt < 4; ++nt)
#pragma unroll
            for (int kc = 0; kc < 4; ++kc) {
                bf16x8 bk = __builtin_bit_cast(bf16x8,
                    *(const uint4*)&Ks[(nt*16 + l15)*KPAD + kc*32 + quad*8]);
                accS[0][nt] = __builtin_amdgcn_mfma_f32_16x16x32_bf16(aq[0][kc], bk, accS[0][nt], 0, 0, 0);
                accS[1][nt] = __builtin_amdgcn_mfma_f32_16x16x32_bf16(aq[1][kc], bk, accS[1][nt], 0, 0, 0);
            }

        // --- soft-cap (poly tanh) + causal + exp2, accumulate row sums ---
#pragma unroll
        for (int m = 0; m < 2; ++m)
#pragma unroll
            for (int nt = 0; nt < 4; ++nt) {
                const int colg = k0 + nt*16 + l15;
#pragma unroll
                for (int r = 0; r < 4; ++r) {
                    const int rowg = q0 + m*16 + quad*4 + r;
                    float s = accS[m][nt][r];
                    float z = s * 0.02f;          // s/50
                    float u = z * z;              // <= ~0.052
                    float poly = fmaf(u, fmaf(u, fmaf(u, -0.05396825396825397f,
                                           0.13333333333333333f),
                                          -0.3333333333333333f), 1.0f);
                    float p = __builtin_amdgcn_exp2f(s * poly * L2E);
                    p = (colg > rowg) ? 0.f : p;
                    ls[m][r] += p;
                    Ps[(w*32 + m*16 + quad*4 + r)*PPAD + nt*16 + l15] = f2bf(p);
                }
            }

        bf16x8 ap[2][2];
#pragma unroll
        for (int m = 0; m < 2; ++m)
#pragma unroll
            for (int kc = 0; kc < 2; ++kc)
                ap[m][kc] = __builtin_bit_cast(bf16x8,
                    *(const uint4*)&Ps[(w*32 + m*16 + l15)*PPAD + kc*32 + quad*8]);

        // --- O += P V: each bv feeds 2 MFMAs ---
#pragma unroll
        for (int nd = 0; nd < 8; ++nd)
#pragma unroll
            for (int kc = 0; kc < 2; ++kc) {
                bf16x8 bv = __builtin_bit_cast(bf16x8,
                    *(const uint4*)&Vts[(nd*16 + l15)*VPAD + kc*32 + quad*8]);
                accO[0][nd] = __builtin_amdgcn_mfma_f32_16x16x32_bf16(ap[0][kc], bv, accO[0][nd], 0, 0, 0);
                accO[1][nd] = __builtin_amdgcn_mfma_f32_16x16x32_bf16(ap[1][kc], bv, accO[1][nd], 0, 0, 0);
            }
        __syncthreads();
    }

    // --- final row-sum reduction across the 16 l15 lanes ---
#pragma unroll
    for (int m = 0; m < 2; ++m)
#pragma unroll
        for (int r = 0; r < 4; ++r) {
            float v = ls[m][r];
            v += __shfl_xor(v, 1, 64);
            v += __shfl_xor(v, 2, 64);
            v += __shfl_xor(v, 4, 64);
            v += __shfl_xor(v, 8, 64);
            ls[m][r] = v;
        }

#pragma unroll
    for (int m = 0; m < 2; ++m)
#pragma unroll
        for (int r = 0; r < 4; ++r) {
            float invl = 1.f / ls[m][r];
            u16* yp = y + (size_t)(b*T_SEQ + q0 + m*16 + quad*4 + r) * C_DIM + h*DH;
#pragma unroll
            for (int nd = 0; nd < 8; ++nd)
                yp[nd*16 + l15] = f2bf(accO[m][nd][r] * invl);
        }
}

// ---------------------------------------------------------------------------
extern "C" void kernel_launch(void* const* d_in, const int* in_sizes, int n_in,
                              void* d_out, int out_size, void* d_ws, size_t ws_size,
                              hipStream_t stream) {
    const float* x  = (const float*)d_in[0];
    const float* Wq = (const float*)d_in[1];
    const float* Wk = (const float*)d_in[2];
    const float* Wv = (const float*)d_in[3];
    const float* Wo = (const float*)d_in[4];
    const float* bo = (const float*)d_in[5];
    const float* qw = (const float*)d_in[6];
    const float* kw = (const float*)d_in[7];
    float* out = (float*)d_out;

    const size_t qE = (size_t)BATCH * T_SEQ * NH * DH;   // 8,388,608
    const size_t kE = (size_t)BATCH * T_SEQ * NG * DH;   // 2,097,152
    const size_t wqE = (size_t)C_DIM * C_DIM;            // 4,194,304
    const size_t wkE = (size_t)(NG*DH) * C_DIM;          // 1,048,576

    float* qf  = (float*)d_ws;          // qE floats
    float* kf  = qf + qE;               // kE floats
    float* vf  = kf + kE;               // kE floats
    u16*   qh  = (u16*)(vf + kE);       // qE
    u16*   khb = qh + qE;               // kE
    u16*   vtb = khb + kE;              // kE
    u16*   xh  = vtb + kE;              // qE
    u16*   wqh = xh + qE;               // wqE
    u16*   wkh = wqh + wqE;             // wkE
    u16*   wvh = wkh + wkE;             // wkE
    u16*   woh = (u16*)kf;              // wqE (reuses kf: dead after rmsnorm)
    u16*   yh  = (u16*)qf;              // qE  (reuses qf: dead after rmsnorm)

    const int M = BATCH * T_SEQ;   // 4096
    dim3 blk(256);

    cast_multi<<<dim3(7168), blk, 0, stream>>>(x, Wq, Wk, Wv, xh, wqh, wkh, wvh);

    gemm_qkv<<<dim3(24, M/128), blk, 0, stream>>>(xh, wqh, wkh, wvh, qf, kf, vf);

    rmsnorm_rope_qk<<<dim3(M*NH/4 + M*NG/4), blk, 0, stream>>>(qf, kf, qw, kw, qh, khb);
    v_cast_transpose<<<dim3(T_SEQ/64, BATCH*NG), blk, 0, stream>>>(vf, vtb);

    cast_f32_bf16<<<dim3(wqE/8/256), blk, 0, stream>>>(Wo, woh, wqE/8);

    flash_attn_mfma<<<dim3(T_SEQ/32, BATCH*NG), blk, 0, stream>>>(qh, khb, vtb, yh);

    gemm_nt_bf16<<<dim3(C_DIM/128, M/128), blk, 0, stream>>>(yh, woh, bo, out, C_DIM, C_DIM);
}

// Round 8
// 385.092 us; speedup vs baseline: 1.2020x; 1.2020x over previous
//
#include <hip/hip_runtime.h>
#include <math.h>

#define T_SEQ 2048
#define C_DIM 2048
#define NH    16
#define NG    4
#define DH    128
#define BATCH 2

typedef unsigned short u16;
typedef __bf16 bf16_t;
typedef bf16_t bf16x8 __attribute__((ext_vector_type(8)));
typedef float  f32x4  __attribute__((ext_vector_type(4)));

static __device__ __forceinline__ u16 f2bf(float f) {
    return __builtin_bit_cast(u16, (__bf16)f);
}

// async global->LDS, 16B per lane. lds must be wave-uniform base; HW adds lane*16.
static __device__ __forceinline__ void gll16(const void* g, void* lds) {
    __builtin_amdgcn_global_load_lds(
        (const __attribute__((address_space(1))) void*)(unsigned long long)(g),
        (__attribute__((address_space(3))) void*)(unsigned int)(unsigned long long)(lds),
        16, 0, 0);
}

// ---------------------------------------------------------------------------
// fused fp32->bf16 cast for x, Wq, Wk, Wv (8 elems/thread, flat if-chain)
// chunk counts: x 1048576 | Wq 524288 | Wk 131072 | Wv 131072  (sum = 7168*256)
// ---------------------------------------------------------------------------
__global__ __launch_bounds__(256)
void cast_multi(const float* __restrict__ x,  const float* __restrict__ wq,
                const float* __restrict__ wk, const float* __restrict__ wv,
                u16* __restrict__ xo, u16* __restrict__ wqo,
                u16* __restrict__ wko, u16* __restrict__ wvo) {
    int i = blockIdx.x * 256 + threadIdx.x;
    const float* src; u16* dst; int off;
    if (i < 1048576)      { src = x;  dst = xo;  off = i; }
    else if (i < 1572864) { src = wq; dst = wqo; off = i - 1048576; }
    else if (i < 1703936) { src = wk; dst = wko; off = i - 1572864; }
    else                  { src = wv; dst = wvo; off = i - 1703936; }
    const float4* p = (const float4*)src + (size_t)off * 2;
    float4 a = p[0], b = p[1];
    u16 u[8] = {f2bf(a.x), f2bf(a.y), f2bf(a.z), f2bf(a.w),
                f2bf(b.x), f2bf(b.y), f2bf(b.z), f2bf(b.w)};
    *(uint4*)(dst + (size_t)off * 8) = *(const uint4*)u;
}

__global__ __launch_bounds__(256)
void cast_f32_bf16(const float* __restrict__ in, u16* __restrict__ out, int n8) {
    int i = blockIdx.x * 256 + threadIdx.x;
    if (i >= n8) return;
    const float4* p = (const float4*)in + (size_t)i * 2;
    float4 a = p[0], b = p[1];
    u16 u[8] = {f2bf(a.x), f2bf(a.y), f2bf(a.z), f2bf(a.w),
                f2bf(b.x), f2bf(b.y), f2bf(b.z), f2bf(b.w)};
    *(uint4*)(out + (size_t)i * 8) = *(const uint4*)u;
}

// ---------------------------------------------------------------------------
// C(fp32, M x N) = A_bf16(M,K) @ B_bf16(N,K)^T (+bias)
// 128x128 tile, BK=32, 4 waves, each wave 64x64 (4x4 MFMA 16x16x32).
// ---------------------------------------------------------------------------
static __device__ __forceinline__ void gemm_body(
        u16* As, u16* Bs,
        const u16* __restrict__ A, const u16* __restrict__ B,
        const float* __restrict__ bias, float* __restrict__ C,
        int N, int K, int m0, int n0) {
    const int t    = threadIdx.x;
    const int lane = t & 63, w = t >> 6;
    const int l15  = lane & 15, quad = lane >> 4;
    const int wr   = w >> 1, wc = w & 1;

    f32x4 acc[4][4];
#pragma unroll
    for (int mt = 0; mt < 4; ++mt)
#pragma unroll
        for (int nt = 0; nt < 4; ++nt) acc[mt][nt] = (f32x4){0.f, 0.f, 0.f, 0.f};

    const int off0 = w*2048 + lane*16;
    const int r0 = off0 >> 6,          c0 = (off0 & 63) >> 1;
    const int r1 = (off0+1024) >> 6,   c1 = ((off0+1024) & 63) >> 1;
    const u16* Ag0 = A + (size_t)(m0 + r0) * K + c0;
    const u16* Ag1 = A + (size_t)(m0 + r1) * K + c1;
    const u16* Bg0 = B + (size_t)(n0 + r0) * K + c0;
    const u16* Bg1 = B + (size_t)(n0 + r1) * K + c1;
    char* AsB = (char*)As; char* BsB = (char*)Bs;
    const int ldsOff0 = w*2048, ldsOff1 = w*2048 + 1024;

    for (int k0 = 0; k0 < K; k0 += 32) {
        gll16(Ag0 + k0, AsB + ldsOff0);
        gll16(Ag1 + k0, AsB + ldsOff1);
        gll16(Bg0 + k0, BsB + ldsOff0);
        gll16(Bg1 + k0, BsB + ldsOff1);
        __syncthreads();
        bf16x8 af[4], bf[4];
#pragma unroll
        for (int mt = 0; mt < 4; ++mt)
            af[mt] = __builtin_bit_cast(bf16x8,
                *(const uint4*)&As[(wr*64 + mt*16 + l15)*32 + quad*8]);
#pragma unroll
        for (int nt = 0; nt < 4; ++nt)
            bf[nt] = __builtin_bit_cast(bf16x8,
                *(const uint4*)&Bs[(wc*64 + nt*16 + l15)*32 + quad*8]);
#pragma unroll
        for (int mt = 0; mt < 4; ++mt)
#pragma unroll
            for (int nt = 0; nt < 4; ++nt)
                acc[mt][nt] = __builtin_amdgcn_mfma_f32_16x16x32_bf16(
                                  af[mt], bf[nt], acc[mt][nt], 0, 0, 0);
        __syncthreads();
    }

#pragma unroll
    for (int mt = 0; mt < 4; ++mt)
#pragma unroll
        for (int nt = 0; nt < 4; ++nt) {
            const int col = n0 + wc*64 + nt*16 + l15;
            const float bv = bias ? bias[col] : 0.f;
#pragma unroll
            for (int r = 0; r < 4; ++r) {
                const int row = m0 + wr*64 + mt*16 + quad*4 + r;
                C[(size_t)row * N + col] = acc[mt][nt][r] + bv;
            }
        }
}

__global__ __launch_bounds__(256)
void gemm_nt_bf16(const u16* __restrict__ A, const u16* __restrict__ B,
                  const float* __restrict__ bias, float* __restrict__ C,
                  int N, int K) {
    __shared__ __align__(16) u16 As[128*32];
    __shared__ __align__(16) u16 Bs[128*32];
    gemm_body(As, Bs, A, B, bias, C, N, K, blockIdx.y*128, blockIdx.x*128);
}

// fused Q/K/V projections: blockIdx.x 0..15 -> Q cols, 16..19 -> K, 20..23 -> V
__global__ __launch_bounds__(256)
void gemm_qkv(const u16* __restrict__ A,  const u16* __restrict__ Bq,
              const u16* __restrict__ Bk, const u16* __restrict__ Bv,
              float* __restrict__ Cq, float* __restrict__ Ck, float* __restrict__ Cv) {
    __shared__ __align__(16) u16 As[128*32];
    __shared__ __align__(16) u16 Bs[128*32];
    const int bx = blockIdx.x;
    const u16* B; float* C; int N, n0;
    if (bx < 16)      { B = Bq; C = Cq; N = 2048; n0 = bx * 128; }
    else if (bx < 20) { B = Bk; C = Ck; N = 512;  n0 = (bx-16) * 128; }
    else              { B = Bv; C = Cv; N = 512;  n0 = (bx-20) * 128; }
    gemm_body(As, Bs, A, B, nullptr, C, N, 2048, blockIdx.y*128, n0);
}

// ---------------------------------------------------------------------------
// Fused RMSNorm + RoPE for q and k, fp32 in -> bf16 out.
// blocks [0, 16384): q rows; [16384, 20480): k rows. One wave per D=128 row.
// ---------------------------------------------------------------------------
__global__ __launch_bounds__(256)
void rmsnorm_rope_qk(const float* __restrict__ qf, const float* __restrict__ kf,
                     const float* __restrict__ qw, const float* __restrict__ kw,
                     u16* __restrict__ qo, u16* __restrict__ ko) {
    const int blk  = blockIdx.x;
    const int sub  = threadIdx.x >> 6;
    const int lane = threadIdx.x & 63;
    const float* in; const float* w; u16* out; int row, nheads; float scale;
    if (blk < 16384) {
        in = qf; w = qw; out = qo; nheads = NH; scale = 0.08838834764831845f;
        row = blk * 4 + sub;
    } else {
        in = kf; w = kw; out = ko; nheads = NG; scale = 1.0f;
        row = (blk - 16384) * 4 + sub;
    }
    const float* p = in + (size_t)row * 128;
    float x1 = p[lane], x2 = p[lane + 64];
    float ss = x1*x1 + x2*x2;
#pragma unroll
    for (int off = 32; off >= 1; off >>= 1) ss += __shfl_xor(ss, off, 64);
    float inv = 1.0f / (sqrtf(ss * (1.0f/128.0f)) + 1e-6f);
    float x1n = w[lane]      * x1 * inv;
    float x2n = w[lane + 64] * x2 * inv;
    int tpos = (row / nheads) & (T_SEQ - 1);
    float invfreq = powf(10000.0f, -(float)lane / 64.0f);
    float s, c;
    sincosf((float)tpos * invfreq, &s, &c);
    out[(size_t)row*128 + lane]      = f2bf((x1n * c + x2n * s) * scale);
    out[(size_t)row*128 + lane + 64] = f2bf((x2n * c - x1n * s) * scale);
}

// ---------------------------------------------------------------------------
// V cast fp32->bf16 + transpose: v (B,T,G,D) -> vt (B,G,D,T).
// ---------------------------------------------------------------------------
__global__ __launch_bounds__(256)
void v_cast_transpose(const float* __restrict__ v, u16* __restrict__ vt) {
    __shared__ u16 Lt[128 * 66];
    const int t  = threadIdx.x;
    const int t0 = blockIdx.x * 64;
    const int bg = blockIdx.y;
    const int b  = bg / NG, g = bg % NG;
#pragma unroll
    for (int rep = 0; rep < 8; ++rep) {
        int idx = rep * 256 + t;
        int i   = idx >> 5;
        int c   = idx & 31;
        float4 f = *(const float4*)(v + ((size_t)(b*T_SEQ + t0 + i)*NG + g)*DH + c*4);
        Lt[(c*4+0)*66 + i] = f2bf(f.x);
        Lt[(c*4+1)*66 + i] = f2bf(f.y);
        Lt[(c*4+2)*66 + i] = f2bf(f.z);
        Lt[(c*4+3)*66 + i] = f2bf(f.w);
    }
    __syncthreads();
#pragma unroll
    for (int rep = 0; rep < 4; ++rep) {
        int idx = rep * 256 + t;
        int d = idx >> 3, c = idx & 7;
        const u16* src = &Lt[d*66 + c*8];
        uint4 val;
        val.x = *(const unsigned int*)(src + 0);
        val.y = *(const unsigned int*)(src + 2);
        val.z = *(const unsigned int*)(src + 4);
        val.w = *(const unsigned int*)(src + 6);
        *(uint4*)(vt + ((size_t)(bg*DH + d))*T_SEQ + t0 + c*8) = val;
    }
}

// ---------------------------------------------------------------------------
// MFMA flash attention v4 (reverted from v5: the 2-heads-per-wave variant
// spilled ~77 MB to scratch per dispatch — WRITE_SIZE 16->93 MB, R7).
// Block = 512 thr = 8 waves = 4 heads (one group) x 32 queries.
// GQA-shared K/V staging; chunk pairing balances CU load; K/V tile t+1
// prefetched into VGPRs (16 VGPRs only — no spill at VGPR_Count 80).
// ---------------------------------------------------------------------------
#define KPAD 136
#define VPAD 72
#define PPAD 72

__global__ __launch_bounds__(512)
void flash_attn_mfma(const u16* __restrict__ qh, const u16* __restrict__ kh,
                     const u16* __restrict__ vt, u16* __restrict__ y) {
    __shared__ __align__(16) u16 Ks [64  * KPAD];   // 64 keys x 128 d
    __shared__ __align__(16) u16 Vts[128 * VPAD];   // 128 d  x 64 keys
    __shared__ __align__(16) u16 Ps [128 * PPAD];   // 8 waves x 16 rows x 64 keys

    const int t    = threadIdx.x;
    const int lane = t & 63, w = t >> 6;            // w = 0..7
    const int l15  = lane & 15, quad = lane >> 4;
    const int bg   = blockIdx.y;
    const int b    = bg >> 2, g = bg & 3;
    const int chunk = b ? (int)blockIdx.x : (63 - (int)blockIdx.x);
    const int q0   = chunk * 32;
    const int h    = g * (NH / NG) + (w & 3);
    const int qrow0 = q0 + (w >> 2) * 16;

    const float L2E = 1.4426950408889634f;

    bf16x8 aq[4];
    const u16* qp = qh + ((size_t)(b*T_SEQ + qrow0 + l15) * NH + h) * DH;
#pragma unroll
    for (int kc = 0; kc < 4; ++kc)
        aq[kc] = __builtin_bit_cast(bf16x8, *(const uint4*)(qp + kc*32 + quad*8));

    f32x4 accO[8];
#pragma unroll
    for (int nd = 0; nd < 8; ++nd) accO[nd] = (f32x4){0.f, 0.f, 0.f, 0.f};
    float ls[4] = {0.f, 0.f, 0.f, 0.f};

    // staging geometry (fixed per thread)
    const int kr = t >> 4, kc16 = t & 15;           // K: rows kr, kr+32
    const int vd = t >> 3, vc8  = t & 7;            // V: d-rows vd, vd+64
    const u16* kgb = kh + ((size_t)b*T_SEQ*NG + g)*DH;
    const u16* vgb = vt + ((size_t)(b*NG + g)*DH)*T_SEQ;

    uint4 kreg0, kreg1, vreg0, vreg1;
    {   // prefetch tile 0
        kreg0 = *(const uint4*)(kgb + (size_t)(0 + kr)      * NG*DH + kc16*8);
        kreg1 = *(const uint4*)(kgb + (size_t)(0 + kr + 32) * NG*DH + kc16*8);
        vreg0 = *(const uint4*)(vgb + (size_t)vd       * T_SEQ + 0 + vc8*8);
        vreg1 = *(const uint4*)(vgb + (size_t)(vd + 64)* T_SEQ + 0 + vc8*8);
    }

    const int ktiles = q0 / 64 + 1;
    for (int kt = 0; kt < ktiles; ++kt) {
        // --- regs -> LDS ---
        *(uint4*)&Ks [ kr      *KPAD + kc16*8] = kreg0;
        *(uint4*)&Ks [(kr + 32)*KPAD + kc16*8] = kreg1;
        *(uint4*)&Vts[ vd      *VPAD + vc8*8]  = vreg0;
        *(uint4*)&Vts[(vd + 64)*VPAD + vc8*8]  = vreg1;
        __syncthreads();

        // --- prefetch tile kt+1 (overlaps compute below) ---
        if (kt + 1 < ktiles) {
            const int k1 = (kt + 1) * 64;
            kreg0 = *(const uint4*)(kgb + (size_t)(k1 + kr)      * NG*DH + kc16*8);
            kreg1 = *(const uint4*)(kgb + (size_t)(k1 + kr + 32) * NG*DH + kc16*8);
            vreg0 = *(const uint4*)(vgb + (size_t)vd       * T_SEQ + k1 + vc8*8);
            vreg1 = *(const uint4*)(vgb + (size_t)(vd + 64)* T_SEQ + k1 + vc8*8);
        }

        const int k0 = kt * 64;
        // --- S = Q K^T (16x64 per wave) ---
        f32x4 accS[4];
#pragma unroll
        for (int nt = 0; nt < 4; ++nt) accS[nt] = (f32x4){0.f, 0.f, 0.f, 0.f};
#pragma unroll
        for (int nt = 0; nt < 4; ++nt)
#pragma unroll
            for (int kc = 0; kc < 4; ++kc) {
                bf16x8 bk = __builtin_bit_cast(bf16x8,
                    *(const uint4*)&Ks[(nt*16 + l15)*KPAD + kc*32 + quad*8]);
                accS[nt] = __builtin_amdgcn_mfma_f32_16x16x32_bf16(aq[kc], bk, accS[nt], 0, 0, 0);
            }

        // --- soft-cap (poly tanh) + causal + exp2, accumulate row sums ---
#pragma unroll
        for (int nt = 0; nt < 4; ++nt) {
            const int colg = k0 + nt*16 + l15;
#pragma unroll
            for (int r = 0; r < 4; ++r) {
                const int rowg = qrow0 + quad*4 + r;
                float s = accS[nt][r];
                float z = s * 0.02f;          // s/50
                float u = z * z;              // <= ~0.052
                float poly = fmaf(u, fmaf(u, fmaf(u, -0.05396825396825397f,
                                       0.13333333333333333f),
                                      -0.3333333333333333f), 1.0f);
                float p = __builtin_amdgcn_exp2f(s * poly * L2E);
                p = (colg > rowg) ? 0.f : p;
                ls[r] += p;
                Ps[(w*16 + quad*4 + r)*PPAD + nt*16 + l15] = f2bf(p);
            }
        }

        bf16x8 ap[2];
#pragma unroll
        for (int kc = 0; kc < 2; ++kc)
            ap[kc] = __builtin_bit_cast(bf16x8,
                *(const uint4*)&Ps[(w*16 + l15)*PPAD + kc*32 + quad*8]);

#pragma unroll
        for (int nd = 0; nd < 8; ++nd)
#pragma unroll
            for (int kc = 0; kc < 2; ++kc) {
                bf16x8 bv = __builtin_bit_cast(bf16x8,
                    *(const uint4*)&Vts[(nd*16 + l15)*VPAD + kc*32 + quad*8]);
                accO[nd] = __builtin_amdgcn_mfma_f32_16x16x32_bf16(ap[kc], bv, accO[nd], 0, 0, 0);
            }
        __syncthreads();
    }

    // --- final row-sum reduction across the 16 l15 lanes ---
#pragma unroll
    for (int r = 0; r < 4; ++r) {
        float v = ls[r];
        v += __shfl_xor(v, 1, 64);
        v += __shfl_xor(v, 2, 64);
        v += __shfl_xor(v, 4, 64);
        v += __shfl_xor(v, 8, 64);
        ls[r] = v;
    }

#pragma unroll
    for (int r = 0; r < 4; ++r) {
        float invl = 1.f / ls[r];
        u16* yp = y + (size_t)(b*T_SEQ + qrow0 + quad*4 + r) * C_DIM + h*DH;
#pragma unroll
        for (int nd = 0; nd < 8; ++nd)
            yp[nd*16 + l15] = f2bf(accO[nd][r] * invl);
    }
}

// ---------------------------------------------------------------------------
extern "C" void kernel_launch(void* const* d_in, const int* in_sizes, int n_in,
                              void* d_out, int out_size, void* d_ws, size_t ws_size,
                              hipStream_t stream) {
    const float* x  = (const float*)d_in[0];
    const float* Wq = (const float*)d_in[1];
    const float* Wk = (const float*)d_in[2];
    const float* Wv = (const float*)d_in[3];
    const float* Wo = (const float*)d_in[4];
    const float* bo = (const float*)d_in[5];
    const float* qw = (const float*)d_in[6];
    const float* kw = (const float*)d_in[7];
    float* out = (float*)d_out;

    const size_t qE = (size_t)BATCH * T_SEQ * NH * DH;   // 8,388,608
    const size_t kE = (size_t)BATCH * T_SEQ * NG * DH;   // 2,097,152
    const size_t wqE = (size_t)C_DIM * C_DIM;            // 4,194,304

    float* qf  = (float*)d_ws;          // qE floats
    float* kf  = qf + qE;               // kE floats
    float* vf  = kf + kE;               // kE floats
    u16*   qh  = (u16*)(vf + kE);       // qE
    u16*   khb = qh + qE;               // kE
    u16*   vtb = khb + kE;              // kE
    u16*   xh  = vtb + kE;              // qE
    u16*   wqh = xh + qE;               // wqE
    u16*   wkh = wqh + wqE;             // wkE
    u16*   wvh = wkh + (size_t)(NG*DH)*C_DIM;            // wkE
    u16*   woh = (u16*)kf;              // wqE (reuses kf: dead after rmsnorm)
    u16*   yh  = (u16*)qf;              // qE  (reuses qf: dead after rmsnorm)

    const int M = BATCH * T_SEQ;   // 4096
    dim3 blk(256);

    cast_multi<<<dim3(7168), blk, 0, stream>>>(x, Wq, Wk, Wv, xh, wqh, wkh, wvh);

    gemm_qkv<<<dim3(24, M/128), blk, 0, stream>>>(xh, wqh, wkh, wvh, qf, kf, vf);

    rmsnorm_rope_qk<<<dim3(M*NH/4 + M*NG/4), blk, 0, stream>>>(qf, kf, qw, kw, qh, khb);
    v_cast_transpose<<<dim3(T_SEQ/64, BATCH*NG), blk, 0, stream>>>(vf, vtb);

    cast_f32_bf16<<<dim3(wqE/8/256), blk, 0, stream>>>(Wo, woh, wqE/8);

    flash_attn_mfma<<<dim3(T_SEQ/32, BATCH*NG), dim3(512), 0, stream>>>(qh, khb, vtb, yh);

    gemm_nt_bf16<<<dim3(C_DIM/128, M/128), blk, 0, stream>>>(yh, woh, bo, out, C_DIM, C_DIM);
}